// Round 1
// baseline (205.410 us; speedup 1.0000x reference)
//
#include <hip/hip_runtime.h>
#include <math.h>

// HomoAttention: per (b,n): x[F=8][E=32], z[K=64][F][E]; L2-normalize x,z over E;
// a[k][f] = <zn[k][f], xn[f]>; softmax over k; u[f][e] = sum_k a[k][f] * zn[k][f][e].
// B*N = 2048 blocks of 256 threads. Memory-bound: 512 MB neigh read once.

#define EMB 32
#define NF 8
#define DD 256  // NF*EMB
#define KK 64

__global__ __launch_bounds__(256)
void homo_attn_kernel(const float* __restrict__ features,
                      const float* __restrict__ neigh,
                      float* __restrict__ out)
{
    const int bn = blockIdx.x;
    const int t  = threadIdx.x;
    const int l  = t & 63;   // lane
    const int tg = t >> 6;   // wave id in block (0..3)
    const int f  = l >> 3;   // facet 0..7
    const int sub = l & 7;   // position within facet (4 floats each)

    const float* xp = features + (size_t)bn * DD;
    const float* zp = neigh    + (size_t)bn * (KK * DD);

    // ---- load + normalize x fragment (4 consecutive floats of facet f) ----
    float4 xv = ((const float4*)xp)[l];
    float ss = xv.x*xv.x + xv.y*xv.y + xv.z*xv.z + xv.w*xv.w;
    ss += __shfl_xor(ss, 1);
    ss += __shfl_xor(ss, 2);
    ss += __shfl_xor(ss, 4);          // 8-lane group = one facet's 32 floats
    float xs = 1.0f / fmaxf(sqrtf(ss), 1e-12f);
    xv.x *= xs; xv.y *= xs; xv.z *= xs; xv.w *= xs;

    __shared__ float  a_s[KK * NF];   // scores [k][f], 2 KB
    __shared__ float4 part[4][64];    // cross-wave partials, 4 KB

    // ---- main loop: each wave handles k = i*4 + tg; z kept in registers ----
    float4 zr[16];
#pragma unroll
    for (int i = 0; i < 16; ++i) {
        const int k = i * 4 + tg;
        float4 z = ((const float4*)(zp + k * DD))[l];   // coalesced 1 KB/wave
        float zss = z.x*z.x + z.y*z.y + z.z*z.z + z.w*z.w;
        zss += __shfl_xor(zss, 1);
        zss += __shfl_xor(zss, 2);
        zss += __shfl_xor(zss, 4);
        float zs = 1.0f / fmaxf(sqrtf(zss), 1e-12f);
        z.x *= zs; z.y *= zs; z.z *= zs; z.w *= zs;
        zr[i] = z;
        float d = z.x*xv.x + z.y*xv.y + z.z*xv.z + z.w*xv.w;
        d += __shfl_xor(d, 1);
        d += __shfl_xor(d, 2);
        d += __shfl_xor(d, 4);
        if (sub == 0) a_s[k * NF + f] = d;
    }
    __syncthreads();

    // ---- softmax over k for this thread's facet (LDS broadcast reads) ----
    float m = -1e30f;
#pragma unroll 8
    for (int k = 0; k < KK; ++k) m = fmaxf(m, a_s[k * NF + f]);
    float denom = 0.0f;
#pragma unroll 8
    for (int k = 0; k < KK; ++k) denom += __expf(a_s[k * NF + f] - m);

    // ---- weighted partial sum over this wave's 16 k's ----
    float4 u = make_float4(0.f, 0.f, 0.f, 0.f);
#pragma unroll
    for (int i = 0; i < 16; ++i) {
        const int k = i * 4 + tg;
        const float w = __expf(a_s[k * NF + f] - m);
        u.x += w * zr[i].x;
        u.y += w * zr[i].y;
        u.z += w * zr[i].z;
        u.w += w * zr[i].w;
    }
    part[tg][l] = u;
    __syncthreads();

    // ---- combine 4 wave partials, divide by denom, store ----
    if (tg == 0) {
        float4 r0 = part[0][l], r1 = part[1][l], r2 = part[2][l], r3 = part[3][l];
        const float inv = 1.0f / denom;
        float4 o;
        o.x = (r0.x + r1.x + r2.x + r3.x) * inv;
        o.y = (r0.y + r1.y + r2.y + r3.y) * inv;
        o.z = (r0.z + r1.z + r2.z + r3.z) * inv;
        o.w = (r0.w + r1.w + r2.w + r3.w) * inv;
        ((float4*)(out + (size_t)bn * DD))[l] = o;
    }
}

extern "C" void kernel_launch(void* const* d_in, const int* in_sizes, int n_in,
                              void* d_out, int out_size, void* d_ws, size_t ws_size,
                              hipStream_t stream) {
    const float* features = (const float*)d_in[0];
    const float* neigh    = (const float*)d_in[1];
    float* out            = (float*)d_out;
    const int BN = in_sizes[0] / DD;   // 128*16 = 2048
    homo_attn_kernel<<<BN, 256, 0, stream>>>(features, neigh, out);
}

// Round 2
// 205.394 us; speedup vs baseline: 1.0001x; 1.0001x over previous
//
#include <hip/hip_runtime.h>
#include <math.h>

// HomoAttention: per (b,n): x[F=8][E=32], z[K=64][F][E]; L2-normalize x,z over E;
// a[k][f] = <zn[k][f], xn[f]>; softmax over k; u[f][e] = sum_k a[k][f] * zn[k][f][e].
// B*N = 2048 blocks of 256 threads. Memory-bound: 512 MB neigh read once.
//
// R2: batch all 16 z-loads per wave BEFORE any use, pinned with sched_barrier(0).
// R1 evidence: 205 us == 64 serialized 900-cyc loads/block; waves had ~1 load in
// flight because load->shfl-reduce per iteration forced vmcnt(0) each k.

#define EMB 32
#define NF 8
#define DD 256  // NF*EMB
#define KK 64

__global__ __launch_bounds__(256)
void homo_attn_kernel(const float* __restrict__ features,
                      const float* __restrict__ neigh,
                      float* __restrict__ out)
{
    const int bn = blockIdx.x;
    const int t  = threadIdx.x;
    const int l  = t & 63;   // lane
    const int tg = t >> 6;   // wave id in block (0..3)
    const int f  = l >> 3;   // facet 0..7
    const int sub = l & 7;   // position within facet (4 floats each)

    const float* xp = features + (size_t)bn * DD;
    const float* zp = neigh    + (size_t)bn * (KK * DD);

    // ---- Phase A: issue x load + all 16 z loads back-to-back (17 in flight) ----
    float4 xv = ((const float4*)xp)[l];
    float4 zr[16];
#pragma unroll
    for (int i = 0; i < 16; ++i) {
        const int k = i * 4 + tg;
        zr[i] = ((const float4*)(zp + k * DD))[l];   // coalesced 1 KB/wave
    }
    __builtin_amdgcn_sched_barrier(0);   // nothing (esp. waitcnt-forcing uses) crosses up

    // ---- normalize x fragment (4 consecutive floats of facet f) ----
    float ss = xv.x*xv.x + xv.y*xv.y + xv.z*xv.z + xv.w*xv.w;
    ss += __shfl_xor(ss, 1);
    ss += __shfl_xor(ss, 2);
    ss += __shfl_xor(ss, 4);          // 8-lane group = one facet's 32 floats
    float xs = 1.0f / fmaxf(sqrtf(ss), 1e-12f);
    xv.x *= xs; xv.y *= xs; xv.z *= xs; xv.w *= xs;

    __shared__ float  a_s[KK * NF];   // scores [k][f], 2 KB
    __shared__ float4 part[4][64];    // cross-wave partials, 4 KB

    // ---- Phase B: normalize z, cosine scores ----
#pragma unroll
    for (int i = 0; i < 16; ++i) {
        const int k = i * 4 + tg;
        float4 z = zr[i];
        float zss = z.x*z.x + z.y*z.y + z.z*z.z + z.w*z.w;
        zss += __shfl_xor(zss, 1);
        zss += __shfl_xor(zss, 2);
        zss += __shfl_xor(zss, 4);
        float zs = 1.0f / fmaxf(sqrtf(zss), 1e-12f);
        z.x *= zs; z.y *= zs; z.z *= zs; z.w *= zs;
        zr[i] = z;
        float d = z.x*xv.x + z.y*xv.y + z.z*xv.z + z.w*xv.w;
        d += __shfl_xor(d, 1);
        d += __shfl_xor(d, 2);
        d += __shfl_xor(d, 4);
        if (sub == 0) a_s[k * NF + f] = d;
    }
    __syncthreads();

    // ---- softmax over k for this thread's facet (LDS broadcast reads) ----
    float m = -1e30f;
#pragma unroll 8
    for (int k = 0; k < KK; ++k) m = fmaxf(m, a_s[k * NF + f]);
    float denom = 0.0f;
#pragma unroll 8
    for (int k = 0; k < KK; ++k) denom += __expf(a_s[k * NF + f] - m);

    // ---- weighted partial sum over this wave's 16 k's ----
    float4 u = make_float4(0.f, 0.f, 0.f, 0.f);
#pragma unroll
    for (int i = 0; i < 16; ++i) {
        const int k = i * 4 + tg;
        const float w = __expf(a_s[k * NF + f] - m);
        u.x += w * zr[i].x;
        u.y += w * zr[i].y;
        u.z += w * zr[i].z;
        u.w += w * zr[i].w;
    }
    part[tg][l] = u;
    __syncthreads();

    // ---- combine 4 wave partials, divide by denom, store ----
    if (tg == 0) {
        float4 r0 = part[0][l], r1 = part[1][l], r2 = part[2][l], r3 = part[3][l];
        const float inv = 1.0f / denom;
        float4 o;
        o.x = (r0.x + r1.x + r2.x + r3.x) * inv;
        o.y = (r0.y + r1.y + r2.y + r3.y) * inv;
        o.z = (r0.z + r1.z + r2.z + r3.z) * inv;
        o.w = (r0.w + r1.w + r2.w + r3.w) * inv;
        ((float4*)(out + (size_t)bn * DD))[l] = o;
    }
}

extern "C" void kernel_launch(void* const* d_in, const int* in_sizes, int n_in,
                              void* d_out, int out_size, void* d_ws, size_t ws_size,
                              hipStream_t stream) {
    const float* features = (const float*)d_in[0];
    const float* neigh    = (const float*)d_in[1];
    float* out            = (float*)d_out;
    const int BN = in_sizes[0] / DD;   // 128*16 = 2048
    homo_attn_kernel<<<BN, 256, 0, stream>>>(features, neigh, out);
}

// Round 4
// 195.910 us; speedup vs baseline: 1.0485x; 1.0484x over previous
//
#include <hip/hip_runtime.h>
#include <math.h>

// HomoAttention: per (b,n): x[F=8][E=32], z[K=64][F][E]; L2-normalize x,z over E;
// a[k][f] = <zn[k][f], xn[f]>; softmax over k; u[f][e] = sum_k a[k][f] * zn[k][f][e].
// B*N = 2048 blocks of 256 threads. Memory-bound: 512 MB neigh read once.
//
// R4: R3 intent (nontemporal neigh loads) with compile fix: clang's
// __builtin_nontemporal_load needs a native vector type, not HIP_vector_type.
// Theory: timed iteration is [512MB d_ws 0xAA fill -> kernel]; cached neigh
// reads evict the fill's dirty L3 lines, dragging ~300MB writebacks into the
// kernel window (K~127us). nt loads skip L2/L3 allocation -> pure-read stream.

#define EMB 32
#define NF 8
#define DD 256  // NF*EMB
#define KK 64

typedef float nfloat4 __attribute__((ext_vector_type(4)));

__global__ __launch_bounds__(256)
void homo_attn_kernel(const float* __restrict__ features,
                      const float* __restrict__ neigh,
                      float* __restrict__ out)
{
    const int bn = blockIdx.x;
    const int t  = threadIdx.x;
    const int l  = t & 63;   // lane
    const int tg = t >> 6;   // wave id in block (0..3)
    const int f  = l >> 3;   // facet 0..7
    const int sub = l & 7;   // position within facet (4 floats each)

    const float* xp = features + (size_t)bn * DD;
    const float* zp = neigh    + (size_t)bn * (KK * DD);

    // ---- Phase A: issue x load + all 16 z loads back-to-back (17 in flight) ----
    nfloat4 xv = ((const nfloat4*)xp)[l];
    nfloat4 zr[16];
#pragma unroll
    for (int i = 0; i < 16; ++i) {
        const int k = i * 4 + tg;
        zr[i] = __builtin_nontemporal_load(((const nfloat4*)(zp + k * DD)) + l);
    }
    __builtin_amdgcn_sched_barrier(0);   // keep the load batch intact

    // ---- normalize x fragment (4 consecutive floats of facet f) ----
    float ss = xv.x*xv.x + xv.y*xv.y + xv.z*xv.z + xv.w*xv.w;
    ss += __shfl_xor(ss, 1);
    ss += __shfl_xor(ss, 2);
    ss += __shfl_xor(ss, 4);          // 8-lane group = one facet's 32 floats
    float xs = 1.0f / fmaxf(sqrtf(ss), 1e-12f);
    xv *= xs;

    __shared__ float   a_s[KK * NF];   // scores [k][f], 2 KB
    __shared__ nfloat4 part[4][64];    // cross-wave partials, 4 KB

    // ---- Phase B: normalize z, cosine scores ----
#pragma unroll
    for (int i = 0; i < 16; ++i) {
        const int k = i * 4 + tg;
        nfloat4 z = zr[i];
        float zss = z.x*z.x + z.y*z.y + z.z*z.z + z.w*z.w;
        zss += __shfl_xor(zss, 1);
        zss += __shfl_xor(zss, 2);
        zss += __shfl_xor(zss, 4);
        float zs = 1.0f / fmaxf(sqrtf(zss), 1e-12f);
        z *= zs;
        zr[i] = z;
        float d = z.x*xv.x + z.y*xv.y + z.z*xv.z + z.w*xv.w;
        d += __shfl_xor(d, 1);
        d += __shfl_xor(d, 2);
        d += __shfl_xor(d, 4);
        if (sub == 0) a_s[k * NF + f] = d;
    }
    __syncthreads();

    // ---- softmax over k for this thread's facet (LDS broadcast reads) ----
    float m = -1e30f;
#pragma unroll 8
    for (int k = 0; k < KK; ++k) m = fmaxf(m, a_s[k * NF + f]);
    float denom = 0.0f;
#pragma unroll 8
    for (int k = 0; k < KK; ++k) denom += __expf(a_s[k * NF + f] - m);

    // ---- weighted partial sum over this wave's 16 k's ----
    nfloat4 u = (nfloat4)(0.f, 0.f, 0.f, 0.f);
#pragma unroll
    for (int i = 0; i < 16; ++i) {
        const int k = i * 4 + tg;
        const float w = __expf(a_s[k * NF + f] - m);
        u += w * zr[i];
    }
    part[tg][l] = u;
    __syncthreads();

    // ---- combine 4 wave partials, divide by denom, store ----
    if (tg == 0) {
        nfloat4 r = part[0][l] + part[1][l] + part[2][l] + part[3][l];
        r *= (1.0f / denom);
        __builtin_nontemporal_store(r, ((nfloat4*)(out + (size_t)bn * DD)) + l);
    }
}

extern "C" void kernel_launch(void* const* d_in, const int* in_sizes, int n_in,
                              void* d_out, int out_size, void* d_ws, size_t ws_size,
                              hipStream_t stream) {
    const float* features = (const float*)d_in[0];
    const float* neigh    = (const float*)d_in[1];
    float* out            = (float*)d_out;
    const int BN = in_sizes[0] / DD;   // 128*16 = 2048
    homo_attn_kernel<<<BN, 256, 0, stream>>>(features, neigh, out);
}